// Round 2
// baseline (469.266 us; speedup 1.0000x reference)
//
#include <hip/hip_runtime.h>

typedef unsigned short u16;
typedef unsigned int u32;
typedef __attribute__((ext_vector_type(8))) short short8;
typedef __attribute__((ext_vector_type(4))) float f32x4;
typedef __attribute__((ext_vector_type(4))) unsigned short u16x4;

__device__ __forceinline__ u16 f2bf(float f) {
    u32 u = __float_as_uint(f);
    return (u16)((u + 0x7FFFu + ((u >> 16) & 1u)) >> 16);
}

// async global->LDS, 16B per lane. LDS dest must be wave-uniform base + lane*16.
__device__ __forceinline__ void gl2lds16(const u16* g, u16* l) {
    __builtin_amdgcn_global_load_lds(
        (const __attribute__((address_space(1))) u32*)g,
        (__attribute__((address_space(3))) u32*)l, 16, 0, 0);
}

// ---------------------------------------------------------------------------
// Kernel 0a: NCHW fp32 -> NHWC bf16, vectorized 16B/lane both directions.
// Tile 64ic x 64px. Phase1: f32x4 loads (4 consecutive ic rows/thread),
// bf16-pack, ds_write_b64 into pad-72 tile. Phase2: uint4 LDS read (8 ic),
// uint4 global write.
// ---------------------------------------------------------------------------
__global__ __launch_bounds__(256) void nchw2nhwc(const float* __restrict__ x,
                                                 u16* __restrict__ xb) {
    __shared__ u16 t[64 * 72];
    const int b   = blockIdx.x;
    const int n   = b >> 8;          // 32 images
    const int icb = (b >> 6) & 3;    // 4 blocks of 64 ic
    const int pxb = b & 63;          // 64 blocks of 64 px
    const int ic0 = icb * 64, px0 = pxb * 64;
    const int tid = threadIdx.x;

    const int icq = tid >> 4;            // 0..15 -> rows icq*4..icq*4+3
    const int px4 = (tid & 15) * 4;      // 0,4,...,60
    const float* src = x + (size_t)(n * 256 + ic0 + icq * 4) * 4096 + px0 + px4;
    f32x4 v[4];
#pragma unroll
    for (int rr = 0; rr < 4; ++rr) v[rr] = *(const f32x4*)(src + (size_t)rr * 4096);
#pragma unroll
    for (int j = 0; j < 4; ++j) {
        u16x4 p;
        p.x = f2bf(v[0][j]); p.y = f2bf(v[1][j]);
        p.z = f2bf(v[2][j]); p.w = f2bf(v[3][j]);
        *(u16x4*)(t + (px4 + j) * 72 + icq * 4) = p;   // 8B aligned
    }
    __syncthreads();

    const int c = tid & 7, pxr = tid >> 3;           // 8 ic-chunks x 32 px
    u16* dstb = xb + ((size_t)(n * 4096) + px0) * 256 + ic0 + c * 8;
#pragma unroll
    for (int h = 0; h < 2; ++h) {
        int px = h * 32 + pxr;
        uint4 val = *(const uint4*)(t + px * 72 + c * 8);   // 16B aligned
        *(uint4*)(dstb + (size_t)px * 256) = val;
    }
}

// ---------------------------------------------------------------------------
// Kernel 0b: hypernet weight gen -> bf16, wb[oc][icb(8)][tap(9)][icw(32)].
// Also zeroes the 64B OOB zero-page used by conv's halo masking.
// ---------------------------------------------------------------------------
__global__ __launch_bounds__(256) void wgen(const float* __restrict__ z,
                                            const float* __restrict__ W1,
                                            const float* __restrict__ B1,
                                            const float* __restrict__ W2,
                                            const float* __restrict__ B2,
                                            u16* __restrict__ wb,
                                            u16* __restrict__ zpad) {
    __shared__ float zl[64];
    __shared__ float aL[1024];
    const int l = blockIdx.x;
    const int tid = threadIdx.x;
    if (l == 0 && tid < 32) zpad[tid] = 0;
    if (tid < 64) zl[tid] = z[l * 64 + tid];
    __syncthreads();
#pragma unroll
    for (int i = 0; i < 4; ++i) {
        int idx = i * 256 + tid;            // = b*64 + d
        const float* wrow = W1 + (size_t)idx * 64;
        float s = B1[idx];
        for (int nn = 0; nn < 64; ++nn) s += wrow[nn] * zl[nn];
        aL[idx] = s;
    }
    __syncthreads();
    const int b1 = tid >> 4, b2 = tid & 15;
    const int ob = l >> 4, ib = l & 15;
    const int ic = ib * 16 + b1;
    const int oc = ob * 16 + b2;
    const size_t wbase = (size_t)oc * 2304 + (size_t)(ic >> 5) * 288 + (ic & 31);
    const float* arow = aL + b1 * 64;
#pragma unroll
    for (int tap = 0; tap < 9; ++tap) {
        int kk = b2 * 9 + tap;
        const float* w2row = W2 + (size_t)(b1 * 144 + kk) * 64;
        float s = B2[b1 * 144 + kk];
        for (int d = 0; d < 64; ++d) s += w2row[d] * arow[d];
        wb[wbase + tap * 32] = f2bf(s);
    }
}

// ---------------------------------------------------------------------------
// Kernel 1: implicit-GEMM conv via global_load_lds staging.
// M=oc(256) N=px(131072) K=2304. 128x128 tile, 4 waves, 4x4 MFMA 16x16x32.
// Halo masking = per-lane src redirect to zero-page. XCD swizzle pairs the
// two oc-tiles of one pixel tile onto the same XCD (bid, bid+8).
// ---------------------------------------------------------------------------
__global__ __launch_bounds__(256) void conv_mfma(const u16* __restrict__ xb,
                                                 const u16* __restrict__ wb,
                                                 const u16* __restrict__ zpad,
                                                 float* __restrict__ out) {
    __shared__ __align__(16) u16 As[128 * 32];   // [oc_r][k] 8KB
    __shared__ __align__(16) u16 Bs[128 * 32];   // [px][ic]  8KB

    const int tid = threadIdx.x;
    const int bid = blockIdx.x;
    const int xcd = bid & 7, rest = bid >> 3;
    const int mt = rest & 1, grp = rest >> 1;
    const int nt = grp * 8 + xcd;        // pixel tile 0..1023
    const int n = nt >> 5;               // image
    const int pimg = (nt & 31) << 7;     // 2 rows of 64 px
    const int oc0 = mt << 7;

    const int lane = tid & 63;
    const int wave = tid >> 6;
    const int wm = (wave >> 1) & 1, wn = wave & 1;
    const int lr = lane & 15, lq = lane >> 4;

    // staging chunks: q in {tid, tid+256}; r=q>>2 (row), c=q&3 (16B k-chunk)
    const int r0 = tid >> 2, c0 = tid & 3;
    const int q1 = tid + 256, r1 = q1 >> 2, c1 = q1 & 3;

    const u16* aw0 = wb + (size_t)(oc0 + r0) * 2304 + c0 * 8;
    const u16* aw1 = wb + (size_t)(oc0 + r1) * 2304 + c1 * 8;
    u16* al0 = As + tid * 8;
    u16* al1 = As + (tid + 256) * 8;
    u16* bl0 = Bs + tid * 8;
    u16* bl1 = Bs + (tid + 256) * 8;

    const int po0 = pimg + r0, po1 = pimg + r1;
    const int ho0 = po0 >> 6, wo0 = po0 & 63;
    const int ho1 = po1 >> 6, wo1 = po1 & 63;
    const u16* bx0 = xb + ((size_t)(n * 4096) + po0) * 256 + c0 * 8;
    const u16* bx1 = xb + ((size_t)(n * 4096) + po1) * 256 + c1 * 8;

    bool m0[9], m1[9];
#pragma unroll
    for (int tap = 0; tap < 9; ++tap) {
        const int dh = tap / 3 - 1, dw = tap % 3 - 1;
        m0[tap] = ((unsigned)(ho0 + dh) < 64u) & ((unsigned)(wo0 + dw) < 64u);
        m1[tap] = ((unsigned)(ho1 + dh) < 64u) & ((unsigned)(wo1 + dw) < 64u);
    }

    f32x4 acc[4][4];
    const f32x4 z4 = {0.f, 0.f, 0.f, 0.f};
#pragma unroll
    for (int i = 0; i < 4; ++i)
#pragma unroll
        for (int j = 0; j < 4; ++j) acc[i][j] = z4;

    for (int icb = 0; icb < 8; ++icb) {
#pragma unroll
        for (int tap = 0; tap < 9; ++tap) {
            const int dh = tap / 3 - 1, dw = tap % 3 - 1;
            const int toff = (dh * 64 + dw) * 256 + icb * 32;  // elems into xb
            const int koff = (icb * 9 + tap) * 32;

            gl2lds16(aw0 + koff, al0);
            gl2lds16(aw1 + koff, al1);
            gl2lds16(m0[tap] ? bx0 + toff : zpad, bl0);
            gl2lds16(m1[tap] ? bx1 + toff : zpad, bl1);
            __syncthreads();

            short8 af[4], bfr[4];
#pragma unroll
            for (int i = 0; i < 4; ++i) {
                af[i]  = *(const short8*)(As + (wm * 64 + i * 16 + lr) * 32 + lq * 8);
                bfr[i] = *(const short8*)(Bs + (wn * 64 + i * 16 + lr) * 32 + lq * 8);
            }
#pragma unroll
            for (int i = 0; i < 4; ++i)
#pragma unroll
                for (int j = 0; j < 4; ++j)
                    acc[i][j] = __builtin_amdgcn_mfma_f32_16x16x32_bf16(
                        af[i], bfr[j], acc[i][j], 0, 0, 0);
            __syncthreads();
        }
    }

    // epilogue: C/D layout col=lane&15 (pixel), row=lq*4+reg (oc)
    const size_t outn = (size_t)n * 256 * 4096;
#pragma unroll
    for (int i = 0; i < 4; ++i) {
        int ocb = oc0 + wm * 64 + i * 16 + lq * 4;
#pragma unroll
        for (int j = 0; j < 4; ++j) {
            int po = pimg + wn * 64 + j * 16 + lr;
            float* op = out + outn + (size_t)ocb * 4096 + po;
#pragma unroll
            for (int r = 0; r < 4; ++r) op[(size_t)r * 4096] = acc[i][j][r];
        }
    }
}

extern "C" void kernel_launch(void* const* d_in, const int* in_sizes, int n_in,
                              void* d_out, int out_size, void* d_ws, size_t ws_size,
                              hipStream_t stream) {
    const float* x  = (const float*)d_in[0];   // 32*256*64*64
    const float* z  = (const float*)d_in[1];   // 256*64
    const float* W1 = (const float*)d_in[2];   // 16*64*64
    const float* B1 = (const float*)d_in[3];   // 16*64
    const float* W2 = (const float*)d_in[4];   // 16*144*64
    const float* B2 = (const float*)d_in[5];   // 16*144
    float* out = (float*)d_out;

    u16* xb = (u16*)d_ws;                       // 32*4096*256 bf16 = 64 MiB
    u16* wb = xb + (size_t)32 * 4096 * 256;     // 256*2304 bf16
    u16* zp = wb + (size_t)256 * 2304;          // 64B zero page (16B aligned)
    const size_t need = ((size_t)32 * 4096 * 256 + (size_t)256 * 2304 + 32) * 2;
    if (ws_size < need) return;

    nchw2nhwc<<<dim3(8192), dim3(256), 0, stream>>>(x, xb);
    wgen<<<dim3(256), dim3(256), 0, stream>>>(z, W1, B1, W2, B2, wb, zp);
    conv_mfma<<<dim3(2048), dim3(256), 0, stream>>>(xb, wb, zp, out);
}